// Round 7
// baseline (200.599 us; speedup 1.0000x reference)
//
#include <hip/hip_runtime.h>
#include <math.h>

#define N_CH 128
#define NB_MAX 1024     // max bucket count (n_nodes <= 16384 -> nb <= 1024)
#define ECHUNK 1024     // edges per hist/bin chunk
#define GCHUNK 2048     // records per gather CSR chunk

// ---------------------------------------------------------------------------
// K0: weight prep in float4-friendly layout:
//   V1p[(k>>2)*512 + o*4 + (k&3)] = W[o][k] - W[o][128+k]
//   V2p[(k>>2)*512 + o*4 + (k&3)] = W[o][128+k]
// zero bucket histogram + ticket.
// ---------------------------------------------------------------------------
__global__ __launch_bounds__(256) void prep_kernel(const float* __restrict__ W,
                                                   float* __restrict__ V1,
                                                   float* __restrict__ V2,
                                                   int* __restrict__ binCount,
                                                   int* __restrict__ done,
                                                   int nb) {
    int i = blockIdx.x * 256 + threadIdx.x;
    if (i < N_CH * N_CH) {
        int k = i >> 7, o = i & 127;
        float w1 = W[o * 256 + k];
        float w2 = W[o * 256 + 128 + k];
        int ip = (k >> 2) * 512 + o * 4 + (k & 3);
        V1[ip] = w1 - w2;
        V2[ip] = w2;
    }
    if (i < nb) binCount[i] = 0;
    if (i == 0) *done = 0;
}

// ---------------------------------------------------------------------------
// K1: fused GEMM (16 nodes/block) + LDS bucket histogram (bucket = dst>>4)
//     + last-block ticket scan -> binOffG / binCursor.
// Scan is parallel: 3-4 independent atomic reads per thread + 256-ladder
// (R1's failure was 80 SERIAL atomic round-trips; this is ~1-2 us).
// ---------------------------------------------------------------------------
__global__ __launch_bounds__(256) void gemm_kernel(const float* __restrict__ x,
                                                   const float* __restrict__ V1,
                                                   const float* __restrict__ V2,
                                                   const float* __restrict__ bias,
                                                   const int* __restrict__ dst,
                                                   float* __restrict__ A,
                                                   unsigned short* __restrict__ Bh,
                                                   int* __restrict__ binCount,
                                                   int* __restrict__ binOffG,
                                                   int* __restrict__ binCursor,
                                                   int* __restrict__ done,
                                                   int n_nodes, int n_edges, int nb) {
    __shared__ float xs[16][N_CH];      // 8 KB
    __shared__ int h[NB_MAX];           // 4 KB
    __shared__ int sc[256];             // 1 KB
    __shared__ int isLast;
    const int tid = threadIdx.x;
    const int bid = blockIdx.x;

    // --- LDS bucket histogram of this block's 1024-edge chunk ---
    const int ebase = bid * ECHUNK;
    const int ecnt = min(ECHUNK, n_edges - ebase);
    for (int i = tid; i < nb; i += 256) h[i] = 0;
    __syncthreads();
    if (ecnt > 0) {
        const int j = tid * 4;
        if (j + 4 <= ecnt) {
            int4 d4 = *(const int4*)(dst + ebase + j);
            atomicAdd(&h[d4.x >> 4], 1); atomicAdd(&h[d4.y >> 4], 1);
            atomicAdd(&h[d4.z >> 4], 1); atomicAdd(&h[d4.w >> 4], 1);
        } else {
            for (int q = j; q < ecnt; ++q)
                atomicAdd(&h[dst[ebase + q] >> 4], 1);
        }
    }
    __syncthreads();
    for (int i = tid; i < nb; i += 256)
        if (h[i]) atomicAdd(&binCount[i], h[i]);   // fire-and-forget

    // --- GEMM: 16 nodes per block ---
    const int n0 = bid * 16;
    if (n0 < n_nodes) {
        if (n0 + 16 <= n_nodes) {
            const float4* xg = (const float4*)(x + (size_t)n0 * N_CH);
            float4* xsv = (float4*)&xs[0][0];
            xsv[tid] = xg[tid];
            xsv[tid + 256] = xg[tid + 256];
        } else {
            for (int i = tid; i < 16 * N_CH; i += 256) {
                int n = n0 + (i >> 7);
                (&xs[0][0])[i] = (n < n_nodes) ? x[(size_t)n * N_CH + (i & 127)] : 0.f;
            }
        }
        __syncthreads();

        const int o  = tid & 127;
        const int nh = tid >> 7;            // rows nh*8 .. nh*8+7
        const float bo = bias[o];
        float acc1[8], acc2[8];
        #pragma unroll
        for (int i = 0; i < 8; ++i) { acc1[i] = 0.f; acc2[i] = 0.f; }

        const float* xrow = &xs[nh * 8][0];
        for (int k4 = 0; k4 < N_CH; k4 += 4) {
            float4 w1 = *(const float4*)(V1 + k4 * 128 + o * 4);
            float4 w2 = *(const float4*)(V2 + k4 * 128 + o * 4);
            #pragma unroll
            for (int i = 0; i < 8; ++i) {
                float4 xv = *(const float4*)&xrow[i * N_CH + k4];
                acc1[i] = fmaf(xv.x, w1.x, acc1[i]); acc2[i] = fmaf(xv.x, w2.x, acc2[i]);
                acc1[i] = fmaf(xv.y, w1.y, acc1[i]); acc2[i] = fmaf(xv.y, w2.y, acc2[i]);
                acc1[i] = fmaf(xv.z, w1.z, acc1[i]); acc2[i] = fmaf(xv.z, w2.z, acc2[i]);
                acc1[i] = fmaf(xv.w, w1.w, acc1[i]); acc2[i] = fmaf(xv.w, w2.w, acc2[i]);
            }
        }

        #pragma unroll
        for (int i = 0; i < 8; ++i) {
            int n = n0 + nh * 8 + i;
            if (n < n_nodes) {
                A[(size_t)n * N_CH + o] = acc1[i] + bo;
                // bf16 round-to-nearest-even
                unsigned int bits = __float_as_uint(acc2[i]);
                unsigned int r = (bits + 0x7FFFu + ((bits >> 16) & 1u)) >> 16;
                Bh[(size_t)n * N_CH + o] = (unsigned short)r;
            }
        }
    }

    // --- ticket: last block scans bucket counts -> binOffG / binCursor ---
    __threadfence();
    __syncthreads();
    if (tid == 0) isLast = (atomicAdd(done, 1) == (int)gridDim.x - 1) ? 1 : 0;
    __syncthreads();
    if (!isLast) return;

    const int npt = (nb + 255) >> 8;    // <= 4
    int pv[4]; int s = 0;
    for (int k = 0; k < npt; ++k) {
        int slot = tid * npt + k;
        int c = (slot < nb) ? atomicAdd(&binCount[slot], 0) : 0;   // coherent read
        pv[k] = (c + 3) & ~3;           // 16 B-align each bucket region
        s += pv[k];
    }
    sc[tid] = s;
    __syncthreads();
    #pragma unroll
    for (int off = 1; off < 256; off <<= 1) {
        int u = (tid >= off) ? sc[tid - off] : 0;
        __syncthreads();
        sc[tid] += u;
        __syncthreads();
    }
    int run = sc[tid] - s;
    for (int k = 0; k < npt; ++k) {
        int slot = tid * npt + k;
        if (slot < nb) { binOffG[slot] = run; binCursor[slot] = run; }
        run += pv[k];
    }
    // plain stores: next kernel's boundary provides coherence (proved in R3)
}

// ---------------------------------------------------------------------------
// K2: slim bin scatter (no scan): hist -> rank via LDS atomics -> reserve via
// atomicAdd(binCursor) -> direct packed writes (dst&15)<<14 | src.
// ---------------------------------------------------------------------------
__global__ __launch_bounds__(256) void bin_kernel(const int* __restrict__ src,
                                                  const int* __restrict__ dst,
                                                  int* __restrict__ binCursor,
                                                  unsigned int* __restrict__ binned,
                                                  int n_edges, int nb) {
    __shared__ int hist[NB_MAX];    // 4 KB
    __shared__ int rbase[NB_MAX];   // 4 KB
    const int tid = threadIdx.x;
    const int base = blockIdx.x * ECHUNK;
    const int cnt = min(ECHUNK, n_edges - base);

    for (int i = tid; i < nb; i += 256) hist[i] = 0;
    __syncthreads();

    const int j = tid * 4;
    const int mc = max(0, min(4, cnt - j));
    unsigned int pk[4]; int bb[4], rr[4];
    if (mc == 4) {
        int4 s4 = *(const int4*)(src + base + j);
        int4 d4 = *(const int4*)(dst + base + j);
        int sv[4] = {s4.x, s4.y, s4.z, s4.w};
        int dv[4] = {d4.x, d4.y, d4.z, d4.w};
        #pragma unroll
        for (int k = 0; k < 4; ++k) {
            int b = dv[k] >> 4;
            pk[k] = ((unsigned int)(dv[k] & 15) << 14) | (unsigned int)sv[k];
            bb[k] = b;
            rr[k] = atomicAdd(&hist[b], 1);
        }
    } else {
        for (int k = 0; k < mc; ++k) {
            int sv = src[base + j + k];
            int dv = dst[base + j + k];
            int b = dv >> 4;
            pk[k] = ((unsigned int)(dv & 15) << 14) | (unsigned int)sv;
            bb[k] = b;
            rr[k] = atomicAdd(&hist[b], 1);
        }
    }
    __syncthreads();

    for (int i = tid; i < nb; i += 256) {
        int c = hist[i];
        if (c) rbase[i] = atomicAdd(&binCursor[i], c);
    }
    __syncthreads();

    for (int k = 0; k < mc; ++k)
        binned[rbase[bb[k]] + rr[k]] = pk[k];
}

// ---------------------------------------------------------------------------
// K3: fused CSR-build + gather-max (verified R5 form). One block (256 thr =
// 4 waves) per 16-node bucket; 16 lanes cover one 256 B Bh row (uint4 = 8
// channels/lane); 4 sub-groups -> 4 edges per wave-load, 4 loads in flight.
// ---------------------------------------------------------------------------
#define FOLD4(acc_lo, acc_hi, a, b, c, d)                                        \
    acc_lo = fmaxf(acc_lo, fmaxf(fmaxf(__uint_as_float((a) << 16),               \
                                       __uint_as_float((b) << 16)),              \
                                 fmaxf(__uint_as_float((c) << 16),               \
                                       __uint_as_float((d) << 16))));            \
    acc_hi = fmaxf(acc_hi, fmaxf(fmaxf(__uint_as_float((a) & 0xFFFF0000u),       \
                                       __uint_as_float((b) & 0xFFFF0000u)),      \
                                 fmaxf(__uint_as_float((c) & 0xFFFF0000u),       \
                                       __uint_as_float((d) & 0xFFFF0000u))));

__global__ __launch_bounds__(256) void gather_kernel(
        const float* __restrict__ A,
        const uint4* __restrict__ Bh4,   // n_nodes x 16 uint4 (128 bf16)
        const int* __restrict__ binOffG,
        const int* __restrict__ binCount,
        const unsigned int* __restrict__ binned,
        float* __restrict__ out,
        int n_nodes) {
    __shared__ int lidx[GCHUNK];        // 8 KB
    __shared__ int h16[16], e17[17];
    const int b = blockIdx.x;
    const int tid = threadIdx.x;
    const int wv  = tid >> 6;           // wave 0..3
    const int l   = tid & 63;
    const int sub = l >> 4;             // edge slot within load group
    const int col = l & 15;             // 16 B column within the 256 B row
    const int rbeg = binOffG[b];
    const int cnt  = binCount[b];

    float mlo[4][4], mhi[4][4]; int tcnt[4];
    #pragma unroll
    for (int i = 0; i < 4; ++i) {
        tcnt[i] = 0;
        #pragma unroll
        for (int u = 0; u < 4; ++u) { mlo[i][u] = -INFINITY; mhi[i][u] = -INFINITY; }
    }

    for (int cb = 0; cb < cnt; cb += GCHUNK) {
        const int ccnt = min(GCHUNK, cnt - cb);
        if (tid < 16) h16[tid] = 0;
        __syncthreads();

        // load + rank this chunk's records (8 per thread)
        const int mb = tid * 8;
        const int mc = max(0, min(8, ccnt - mb));
        int myd[8], mys[8], myr[8];
        if (mc == 8) {
            int4 r0 = *(const int4*)((const int*)binned + rbeg + cb + mb);
            int4 r1 = *(const int4*)((const int*)binned + rbeg + cb + mb + 4);
            unsigned int wv8[8] = {(unsigned int)r0.x, (unsigned int)r0.y,
                                   (unsigned int)r0.z, (unsigned int)r0.w,
                                   (unsigned int)r1.x, (unsigned int)r1.y,
                                   (unsigned int)r1.z, (unsigned int)r1.w};
            #pragma unroll
            for (int k = 0; k < 8; ++k) {
                myd[k] = (int)(wv8[k] >> 14);
                mys[k] = (int)(wv8[k] & 16383u);
                myr[k] = atomicAdd(&h16[myd[k]], 1);
            }
        } else {
            for (int k = 0; k < mc; ++k) {
                unsigned int w = binned[rbeg + cb + mb + k];
                myd[k] = (int)(w >> 14);
                mys[k] = (int)(w & 16383u);
                myr[k] = atomicAdd(&h16[myd[k]], 1);
            }
        }
        __syncthreads();
        if (tid == 0) {
            int s = 0;
            #pragma unroll
            for (int k = 0; k < 16; ++k) { e17[k] = s; s += h16[k]; }
            e17[16] = s;
        }
        __syncthreads();
        for (int k = 0; k < mc; ++k)
            lidx[e17[myd[k]] + myr[k]] = mys[k];
        __syncthreads();

        // gather: 4 nodes per wave
        #pragma unroll
        for (int i = 0; i < 4; ++i) {
            const int nl = wv * 4 + i;
            const int c  = h16[nl];
            const int bg = e17[nl];
            tcnt[i] += c;
            int q = 0;
            for (; q + 16 <= c; q += 16) {
                int e0 = lidx[bg + q + sub];
                int e1 = lidx[bg + q + 4 + sub];
                int e2 = lidx[bg + q + 8 + sub];
                int e3 = lidx[bg + q + 12 + sub];
                uint4 w0 = Bh4[(size_t)e0 * 16 + col];
                uint4 w1 = Bh4[(size_t)e1 * 16 + col];
                uint4 w2 = Bh4[(size_t)e2 * 16 + col];
                uint4 w3 = Bh4[(size_t)e3 * 16 + col];
                FOLD4(mlo[i][0], mhi[i][0], w0.x, w1.x, w2.x, w3.x);
                FOLD4(mlo[i][1], mhi[i][1], w0.y, w1.y, w2.y, w3.y);
                FOLD4(mlo[i][2], mhi[i][2], w0.z, w1.z, w2.z, w3.z);
                FOLD4(mlo[i][3], mhi[i][3], w0.w, w1.w, w2.w, w3.w);
            }
            for (; q < c; q += 4) {
                int r = q + sub;
                if (r < c) {
                    uint4 w = Bh4[(size_t)lidx[bg + r] * 16 + col];
                    mlo[i][0] = fmaxf(mlo[i][0], __uint_as_float(w.x << 16));
                    mhi[i][0] = fmaxf(mhi[i][0], __uint_as_float(w.x & 0xFFFF0000u));
                    mlo[i][1] = fmaxf(mlo[i][1], __uint_as_float(w.y << 16));
                    mhi[i][1] = fmaxf(mhi[i][1], __uint_as_float(w.y & 0xFFFF0000u));
                    mlo[i][2] = fmaxf(mlo[i][2], __uint_as_float(w.z << 16));
                    mhi[i][2] = fmaxf(mhi[i][2], __uint_as_float(w.z & 0xFFFF0000u));
                    mlo[i][3] = fmaxf(mlo[i][3], __uint_as_float(w.w << 16));
                    mhi[i][3] = fmaxf(mhi[i][3], __uint_as_float(w.w & 0xFFFF0000u));
                }
            }
        }
        __syncthreads();
    }

    // epilogue: reduce sub-groups, add A, write (isolated nodes -> 0)
    #pragma unroll
    for (int i = 0; i < 4; ++i) {
        const int n = b * 16 + wv * 4 + i;
        if (n >= n_nodes) continue;
        float lo[4], hi[4];
        #pragma unroll
        for (int u = 0; u < 4; ++u) {
            lo[u] = mlo[i][u]; hi[u] = mhi[i][u];
            lo[u] = fmaxf(lo[u], __shfl_xor(lo[u], 16, 64));
            hi[u] = fmaxf(hi[u], __shfl_xor(hi[u], 16, 64));
            lo[u] = fmaxf(lo[u], __shfl_xor(lo[u], 32, 64));
            hi[u] = fmaxf(hi[u], __shfl_xor(hi[u], 32, 64));
        }
        if (sub == 0) {
            float r8[8];
            if (tcnt[i] > 0) {
                const float4* Arow = (const float4*)(A + (size_t)n * N_CH + col * 8);
                float4 a0 = Arow[0], a1 = Arow[1];
                r8[0] = a0.x + lo[0]; r8[1] = a0.y + hi[0];
                r8[2] = a0.z + lo[1]; r8[3] = a0.w + hi[1];
                r8[4] = a1.x + lo[2]; r8[5] = a1.y + hi[2];
                r8[6] = a1.z + lo[3]; r8[7] = a1.w + hi[3];
            } else {
                #pragma unroll
                for (int j2 = 0; j2 < 8; ++j2) r8[j2] = 0.f;
            }
            float4* orow = (float4*)(out + (size_t)n * N_CH + col * 8);
            orow[0] = make_float4(r8[0], r8[1], r8[2], r8[3]);
            orow[1] = make_float4(r8[4], r8[5], r8[6], r8[7]);
        }
    }
}

// ---------------------------------------------------------------------------
extern "C" void kernel_launch(void* const* d_in, const int* in_sizes, int n_in,
                              void* d_out, int out_size, void* d_ws, size_t ws_size,
                              hipStream_t stream) {
    const float* x = (const float*)d_in[0];
    const float* W = (const float*)d_in[1];
    const float* b = (const float*)d_in[2];
    const int*   ei = (const int*)d_in[3];

    const int n_nodes = in_sizes[0] / N_CH;   // 10000
    const int n_edges = in_sizes[3] / 2;      // 640000
    const int nb = (n_nodes + 15) >> 4;       // 625 buckets of 16 nodes
    const int* src = ei;
    const int* dst = ei + n_edges;
    float* out = (float*)d_out;

    char* ws = (char*)d_ws;
    size_t off = 0;
    auto alloc = [&](size_t bytes) -> void* {
        void* p = ws + off;
        off += (bytes + 255) & ~(size_t)255;
        return p;
    };
    float* V1        = (float*)alloc((size_t)N_CH * N_CH * 4);
    float* V2        = (float*)alloc((size_t)N_CH * N_CH * 4);
    float* A         = (float*)alloc((size_t)n_nodes * N_CH * 4);
    unsigned short* Bh = (unsigned short*)alloc((size_t)n_nodes * N_CH * 2);
    int*   binCount  = (int*)alloc((size_t)nb * 4);
    int*   binCursor = (int*)alloc((size_t)nb * 4);
    int*   binOffG   = (int*)alloc((size_t)nb * 4);
    int*   done      = (int*)alloc(256);
    unsigned int* binned = (unsigned int*)alloc(((size_t)n_edges + 4 * NB_MAX) * 4);
    (void)ws_size; (void)n_in; (void)out_size;

    const int nodeChunks = (n_nodes + 15) >> 4;
    const int edgeChunks = (n_edges + ECHUNK - 1) / ECHUNK;
    const int ng = max(nodeChunks, edgeChunks);    // 625

    prep_kernel  <<<64, 256, 0, stream>>>(W, V1, V2, binCount, done, nb);
    gemm_kernel  <<<ng, 256, 0, stream>>>(x, V1, V2, b, dst, A, Bh, binCount,
                                          binOffG, binCursor, done,
                                          n_nodes, n_edges, nb);
    bin_kernel   <<<edgeChunks, 256, 0, stream>>>(src, dst, binCursor, binned,
                                                  n_edges, nb);
    gather_kernel<<<nb, 256, 0, stream>>>(A, (const uint4*)Bh, binOffG, binCount,
                                          binned, out, n_nodes);
}

// Round 8
// 128.182 us; speedup vs baseline: 1.5650x; 1.5650x over previous
//
#include <hip/hip_runtime.h>
#include <math.h>

#define N_CH 128
#define NB_MAX 1024     // max bucket count (n_nodes <= 16384 -> nb <= 1024)
#define ECHUNK 2048     // edges per hist/bin chunk
#define GCHUNK 2048     // records per gather CSR chunk

// ---------------------------------------------------------------------------
// K0: weight prep in float4-friendly layout:
//   V1p[(k>>2)*512 + o*4 + (k&3)] = W[o][k] - W[o][128+k]
//   V2p[(k>>2)*512 + o*4 + (k&3)] = W[o][128+k]
// zero bucket histogram.
// ---------------------------------------------------------------------------
__global__ __launch_bounds__(256) void prep_kernel(const float* __restrict__ W,
                                                   float* __restrict__ V1,
                                                   float* __restrict__ V2,
                                                   int* __restrict__ binCount,
                                                   int nb) {
    int i = blockIdx.x * 256 + threadIdx.x;
    if (i < N_CH * N_CH) {
        int k = i >> 7, o = i & 127;
        float w1 = W[o * 256 + k];
        float w2 = W[o * 256 + 128 + k];
        int ip = (k >> 2) * 512 + o * 4 + (k & 3);
        V1[ip] = w1 - w2;
        V2[ip] = w2;
    }
    if (i < nb) binCount[i] = 0;
}

// ---------------------------------------------------------------------------
// K1: fused GEMM (16 nodes/block, 625 blocks -> 2.44 blocks/CU) + LDS bucket
// histogram (bucket = dst>>4; blocks 0..312 each cover a 2048-edge chunk).
// NO ticket / NO __threadfence (device-scope fence forces an L2 writeback on
// multi-XCD CDNA4 -> R7's 95us stall). Kernel boundary provides coherence.
// ---------------------------------------------------------------------------
__global__ __launch_bounds__(256) void gemm_kernel(const float* __restrict__ x,
                                                   const float* __restrict__ V1,
                                                   const float* __restrict__ V2,
                                                   const float* __restrict__ bias,
                                                   const int* __restrict__ dst,
                                                   float* __restrict__ A,
                                                   unsigned short* __restrict__ Bh,
                                                   int* __restrict__ binCount,
                                                   int n_nodes, int n_edges, int nb) {
    __shared__ float xs[16][N_CH];      // 8 KB
    __shared__ int h[NB_MAX];           // 4 KB
    const int tid = threadIdx.x;
    const int bid = blockIdx.x;

    // --- LDS bucket histogram of this block's 2048-edge chunk ---
    const int ebase = bid * ECHUNK;
    if (ebase < n_edges) {
        const int ecnt = min(ECHUNK, n_edges - ebase);
        for (int i = tid; i < nb; i += 256) h[i] = 0;
        __syncthreads();
        const int j = tid * 8;
        if (j + 8 <= ecnt) {
            int4 d0 = *(const int4*)(dst + ebase + j);
            int4 d1 = *(const int4*)(dst + ebase + j + 4);
            atomicAdd(&h[d0.x >> 4], 1); atomicAdd(&h[d0.y >> 4], 1);
            atomicAdd(&h[d0.z >> 4], 1); atomicAdd(&h[d0.w >> 4], 1);
            atomicAdd(&h[d1.x >> 4], 1); atomicAdd(&h[d1.y >> 4], 1);
            atomicAdd(&h[d1.z >> 4], 1); atomicAdd(&h[d1.w >> 4], 1);
        } else {
            for (int q = j; q < min(j + 8, ecnt); ++q)
                atomicAdd(&h[dst[ebase + q] >> 4], 1);
        }
        __syncthreads();
        for (int i = tid; i < nb; i += 256)
            if (h[i]) atomicAdd(&binCount[i], h[i]);   // fire-and-forget
    }

    // --- GEMM: 16 nodes per block (R7-verified numerics) ---
    const int n0 = bid * 16;
    if (n0 >= n_nodes) return;

    if (n0 + 16 <= n_nodes) {
        const float4* xg = (const float4*)(x + (size_t)n0 * N_CH);
        float4* xsv = (float4*)&xs[0][0];
        xsv[tid] = xg[tid];
        xsv[tid + 256] = xg[tid + 256];
    } else {
        for (int i = tid; i < 16 * N_CH; i += 256) {
            int n = n0 + (i >> 7);
            (&xs[0][0])[i] = (n < n_nodes) ? x[(size_t)n * N_CH + (i & 127)] : 0.f;
        }
    }
    __syncthreads();

    const int o  = tid & 127;
    const int nh = tid >> 7;            // rows nh*8 .. nh*8+7
    const float bo = bias[o];
    float acc1[8], acc2[8];
    #pragma unroll
    for (int i = 0; i < 8; ++i) { acc1[i] = 0.f; acc2[i] = 0.f; }

    const float* xrow = &xs[nh * 8][0];
    for (int k4 = 0; k4 < N_CH; k4 += 4) {
        float4 w1 = *(const float4*)(V1 + k4 * 128 + o * 4);
        float4 w2 = *(const float4*)(V2 + k4 * 128 + o * 4);
        #pragma unroll
        for (int i = 0; i < 8; ++i) {
            float4 xv = *(const float4*)&xrow[i * N_CH + k4];
            acc1[i] = fmaf(xv.x, w1.x, acc1[i]); acc2[i] = fmaf(xv.x, w2.x, acc2[i]);
            acc1[i] = fmaf(xv.y, w1.y, acc1[i]); acc2[i] = fmaf(xv.y, w2.y, acc2[i]);
            acc1[i] = fmaf(xv.z, w1.z, acc1[i]); acc2[i] = fmaf(xv.z, w2.z, acc2[i]);
            acc1[i] = fmaf(xv.w, w1.w, acc1[i]); acc2[i] = fmaf(xv.w, w2.w, acc2[i]);
        }
    }

    #pragma unroll
    for (int i = 0; i < 8; ++i) {
        int n = n0 + nh * 8 + i;
        if (n < n_nodes) {
            A[(size_t)n * N_CH + o] = acc1[i] + bo;
            // bf16 round-to-nearest-even
            unsigned int bits = __float_as_uint(acc2[i]);
            unsigned int r = (bits + 0x7FFFu + ((bits >> 16) & 1u)) >> 16;
            Bh[(size_t)n * N_CH + o] = (unsigned short)r;
        }
    }
}

// ---------------------------------------------------------------------------
// K2: exclusive scan of bucket counts -> binOffG, binCursor. One block, 1024
// threads, one slot/thread, PLAIN coalesced loads (kernel boundary made the
// histogram coherent). Bucket regions padded to 4 records (16 B alignment).
// ---------------------------------------------------------------------------
__global__ __launch_bounds__(1024) void scan_kernel(const int* __restrict__ binCount,
                                                    int* __restrict__ binOffG,
                                                    int* __restrict__ binCursor,
                                                    int nb) {
    __shared__ int sc[1024];
    const int tid = threadIdx.x;
    int c = (tid < nb) ? binCount[tid] : 0;
    int p = (c + 3) & ~3;
    sc[tid] = p;
    __syncthreads();
    #pragma unroll
    for (int off = 1; off < 1024; off <<= 1) {
        int u = (tid >= off) ? sc[tid - off] : 0;
        __syncthreads();
        sc[tid] += u;
        __syncthreads();
    }
    if (tid < nb) {
        int excl = sc[tid] - p;
        binOffG[tid] = excl;
        binCursor[tid] = excl;
    }
}

// ---------------------------------------------------------------------------
// K3: slim bin scatter (no scan): hist -> rank via LDS atomics -> reserve via
// atomicAdd(binCursor) -> direct packed writes (dst&15)<<14 | src.
// ---------------------------------------------------------------------------
__global__ __launch_bounds__(256) void bin_kernel(const int* __restrict__ src,
                                                  const int* __restrict__ dst,
                                                  int* __restrict__ binCursor,
                                                  unsigned int* __restrict__ binned,
                                                  int n_edges, int nb) {
    __shared__ int hist[NB_MAX];    // 4 KB
    __shared__ int rbase[NB_MAX];   // 4 KB
    const int tid = threadIdx.x;
    const int base = blockIdx.x * ECHUNK;
    const int cnt = min(ECHUNK, n_edges - base);

    for (int i = tid; i < nb; i += 256) hist[i] = 0;
    __syncthreads();

    const int j = tid * 8;
    const int mc = max(0, min(8, cnt - j));
    unsigned int pk[8]; int bb[8], rr[8];
    if (mc == 8) {
        int4 s0 = *(const int4*)(src + base + j);
        int4 s1 = *(const int4*)(src + base + j + 4);
        int4 d0 = *(const int4*)(dst + base + j);
        int4 d1 = *(const int4*)(dst + base + j + 4);
        int sv[8] = {s0.x, s0.y, s0.z, s0.w, s1.x, s1.y, s1.z, s1.w};
        int dv[8] = {d0.x, d0.y, d0.z, d0.w, d1.x, d1.y, d1.z, d1.w};
        #pragma unroll
        for (int k = 0; k < 8; ++k) {
            int b = dv[k] >> 4;
            pk[k] = ((unsigned int)(dv[k] & 15) << 14) | (unsigned int)sv[k];
            bb[k] = b;
            rr[k] = atomicAdd(&hist[b], 1);
        }
    } else {
        for (int k = 0; k < mc; ++k) {
            int sv = src[base + j + k];
            int dv = dst[base + j + k];
            int b = dv >> 4;
            pk[k] = ((unsigned int)(dv & 15) << 14) | (unsigned int)sv;
            bb[k] = b;
            rr[k] = atomicAdd(&hist[b], 1);
        }
    }
    __syncthreads();

    for (int i = tid; i < nb; i += 256) {
        int c = hist[i];
        if (c) rbase[i] = atomicAdd(&binCursor[i], c);
    }
    __syncthreads();

    for (int k = 0; k < mc; ++k)
        binned[rbase[bb[k]] + rr[k]] = pk[k];
}

// ---------------------------------------------------------------------------
// K4: fused CSR-build + gather-max (verified R5 form). One block (256 thr =
// 4 waves) per 16-node bucket; 16 lanes cover one 256 B Bh row (uint4 = 8
// channels/lane); 4 sub-groups -> 4 edges per wave-load, 4 loads in flight.
// ---------------------------------------------------------------------------
#define FOLD4(acc_lo, acc_hi, a, b, c, d)                                        \
    acc_lo = fmaxf(acc_lo, fmaxf(fmaxf(__uint_as_float((a) << 16),               \
                                       __uint_as_float((b) << 16)),              \
                                 fmaxf(__uint_as_float((c) << 16),               \
                                       __uint_as_float((d) << 16))));            \
    acc_hi = fmaxf(acc_hi, fmaxf(fmaxf(__uint_as_float((a) & 0xFFFF0000u),       \
                                       __uint_as_float((b) & 0xFFFF0000u)),      \
                                 fmaxf(__uint_as_float((c) & 0xFFFF0000u),       \
                                       __uint_as_float((d) & 0xFFFF0000u))));

__global__ __launch_bounds__(256) void gather_kernel(
        const float* __restrict__ A,
        const uint4* __restrict__ Bh4,   // n_nodes x 16 uint4 (128 bf16)
        const int* __restrict__ binOffG,
        const int* __restrict__ binCount,
        const unsigned int* __restrict__ binned,
        float* __restrict__ out,
        int n_nodes) {
    __shared__ int lidx[GCHUNK];        // 8 KB
    __shared__ int h16[16], e17[17];
    const int b = blockIdx.x;
    const int tid = threadIdx.x;
    const int wv  = tid >> 6;           // wave 0..3
    const int l   = tid & 63;
    const int sub = l >> 4;             // edge slot within load group
    const int col = l & 15;             // 16 B column within the 256 B row
    const int rbeg = binOffG[b];
    const int cnt  = binCount[b];

    float mlo[4][4], mhi[4][4]; int tcnt[4];
    #pragma unroll
    for (int i = 0; i < 4; ++i) {
        tcnt[i] = 0;
        #pragma unroll
        for (int u = 0; u < 4; ++u) { mlo[i][u] = -INFINITY; mhi[i][u] = -INFINITY; }
    }

    for (int cb = 0; cb < cnt; cb += GCHUNK) {
        const int ccnt = min(GCHUNK, cnt - cb);
        if (tid < 16) h16[tid] = 0;
        __syncthreads();

        // load + rank this chunk's records (8 per thread)
        const int mb = tid * 8;
        const int mc = max(0, min(8, ccnt - mb));
        int myd[8], mys[8], myr[8];
        if (mc == 8) {
            int4 r0 = *(const int4*)((const int*)binned + rbeg + cb + mb);
            int4 r1 = *(const int4*)((const int*)binned + rbeg + cb + mb + 4);
            unsigned int wv8[8] = {(unsigned int)r0.x, (unsigned int)r0.y,
                                   (unsigned int)r0.z, (unsigned int)r0.w,
                                   (unsigned int)r1.x, (unsigned int)r1.y,
                                   (unsigned int)r1.z, (unsigned int)r1.w};
            #pragma unroll
            for (int k = 0; k < 8; ++k) {
                myd[k] = (int)(wv8[k] >> 14);
                mys[k] = (int)(wv8[k] & 16383u);
                myr[k] = atomicAdd(&h16[myd[k]], 1);
            }
        } else {
            for (int k = 0; k < mc; ++k) {
                unsigned int w = binned[rbeg + cb + mb + k];
                myd[k] = (int)(w >> 14);
                mys[k] = (int)(w & 16383u);
                myr[k] = atomicAdd(&h16[myd[k]], 1);
            }
        }
        __syncthreads();
        if (tid == 0) {
            int s = 0;
            #pragma unroll
            for (int k = 0; k < 16; ++k) { e17[k] = s; s += h16[k]; }
            e17[16] = s;
        }
        __syncthreads();
        for (int k = 0; k < mc; ++k)
            lidx[e17[myd[k]] + myr[k]] = mys[k];
        __syncthreads();

        // gather: 4 nodes per wave
        #pragma unroll
        for (int i = 0; i < 4; ++i) {
            const int nl = wv * 4 + i;
            const int c  = h16[nl];
            const int bg = e17[nl];
            tcnt[i] += c;
            int q = 0;
            for (; q + 16 <= c; q += 16) {
                int e0 = lidx[bg + q + sub];
                int e1 = lidx[bg + q + 4 + sub];
                int e2 = lidx[bg + q + 8 + sub];
                int e3 = lidx[bg + q + 12 + sub];
                uint4 w0 = Bh4[(size_t)e0 * 16 + col];
                uint4 w1 = Bh4[(size_t)e1 * 16 + col];
                uint4 w2 = Bh4[(size_t)e2 * 16 + col];
                uint4 w3 = Bh4[(size_t)e3 * 16 + col];
                FOLD4(mlo[i][0], mhi[i][0], w0.x, w1.x, w2.x, w3.x);
                FOLD4(mlo[i][1], mhi[i][1], w0.y, w1.y, w2.y, w3.y);
                FOLD4(mlo[i][2], mhi[i][2], w0.z, w1.z, w2.z, w3.z);
                FOLD4(mlo[i][3], mhi[i][3], w0.w, w1.w, w2.w, w3.w);
            }
            for (; q < c; q += 4) {
                int r = q + sub;
                if (r < c) {
                    uint4 w = Bh4[(size_t)lidx[bg + r] * 16 + col];
                    mlo[i][0] = fmaxf(mlo[i][0], __uint_as_float(w.x << 16));
                    mhi[i][0] = fmaxf(mhi[i][0], __uint_as_float(w.x & 0xFFFF0000u));
                    mlo[i][1] = fmaxf(mlo[i][1], __uint_as_float(w.y << 16));
                    mhi[i][1] = fmaxf(mhi[i][1], __uint_as_float(w.y & 0xFFFF0000u));
                    mlo[i][2] = fmaxf(mlo[i][2], __uint_as_float(w.z << 16));
                    mhi[i][2] = fmaxf(mhi[i][2], __uint_as_float(w.z & 0xFFFF0000u));
                    mlo[i][3] = fmaxf(mlo[i][3], __uint_as_float(w.w << 16));
                    mhi[i][3] = fmaxf(mhi[i][3], __uint_as_float(w.w & 0xFFFF0000u));
                }
            }
        }
        __syncthreads();
    }

    // epilogue: reduce sub-groups, add A, write (isolated nodes -> 0)
    #pragma unroll
    for (int i = 0; i < 4; ++i) {
        const int n = b * 16 + wv * 4 + i;
        if (n >= n_nodes) continue;
        float lo[4], hi[4];
        #pragma unroll
        for (int u = 0; u < 4; ++u) {
            lo[u] = mlo[i][u]; hi[u] = mhi[i][u];
            lo[u] = fmaxf(lo[u], __shfl_xor(lo[u], 16, 64));
            hi[u] = fmaxf(hi[u], __shfl_xor(hi[u], 16, 64));
            lo[u] = fmaxf(lo[u], __shfl_xor(lo[u], 32, 64));
            hi[u] = fmaxf(hi[u], __shfl_xor(hi[u], 32, 64));
        }
        if (sub == 0) {
            float r8[8];
            if (tcnt[i] > 0) {
                const float4* Arow = (const float4*)(A + (size_t)n * N_CH + col * 8);
                float4 a0 = Arow[0], a1 = Arow[1];
                r8[0] = a0.x + lo[0]; r8[1] = a0.y + hi[0];
                r8[2] = a0.z + lo[1]; r8[3] = a0.w + hi[1];
                r8[4] = a1.x + lo[2]; r8[5] = a1.y + hi[2];
                r8[6] = a1.z + lo[3]; r8[7] = a1.w + hi[3];
            } else {
                #pragma unroll
                for (int j2 = 0; j2 < 8; ++j2) r8[j2] = 0.f;
            }
            float4* orow = (float4*)(out + (size_t)n * N_CH + col * 8);
            orow[0] = make_float4(r8[0], r8[1], r8[2], r8[3]);
            orow[1] = make_float4(r8[4], r8[5], r8[6], r8[7]);
        }
    }
}

// ---------------------------------------------------------------------------
extern "C" void kernel_launch(void* const* d_in, const int* in_sizes, int n_in,
                              void* d_out, int out_size, void* d_ws, size_t ws_size,
                              hipStream_t stream) {
    const float* x = (const float*)d_in[0];
    const float* W = (const float*)d_in[1];
    const float* b = (const float*)d_in[2];
    const int*   ei = (const int*)d_in[3];

    const int n_nodes = in_sizes[0] / N_CH;   // 10000
    const int n_edges = in_sizes[3] / 2;      // 640000
    const int nb = (n_nodes + 15) >> 4;       // 625 buckets of 16 nodes
    const int* src = ei;
    const int* dst = ei + n_edges;
    float* out = (float*)d_out;

    char* ws = (char*)d_ws;
    size_t off = 0;
    auto alloc = [&](size_t bytes) -> void* {
        void* p = ws + off;
        off += (bytes + 255) & ~(size_t)255;
        return p;
    };
    float* V1        = (float*)alloc((size_t)N_CH * N_CH * 4);
    float* V2        = (float*)alloc((size_t)N_CH * N_CH * 4);
    float* A         = (float*)alloc((size_t)n_nodes * N_CH * 4);
    unsigned short* Bh = (unsigned short*)alloc((size_t)n_nodes * N_CH * 2);
    int*   binCount  = (int*)alloc((size_t)nb * 4);
    int*   binCursor = (int*)alloc((size_t)nb * 4);
    int*   binOffG   = (int*)alloc((size_t)nb * 4);
    unsigned int* binned = (unsigned int*)alloc(((size_t)n_edges + 4 * NB_MAX) * 4);
    (void)ws_size; (void)n_in; (void)out_size;

    const int nodeChunks = (n_nodes + 15) >> 4;                // 625
    const int edgeChunks = (n_edges + ECHUNK - 1) / ECHUNK;    // 313
    const int ng = max(nodeChunks, edgeChunks);                // 625

    prep_kernel  <<<64, 256, 0, stream>>>(W, V1, V2, binCount, nb);
    gemm_kernel  <<<ng, 256, 0, stream>>>(x, V1, V2, b, dst, A, Bh, binCount,
                                          n_nodes, n_edges, nb);
    scan_kernel  <<<1, 1024, 0, stream>>>(binCount, binOffG, binCursor, nb);
    bin_kernel   <<<edgeChunks, 256, 0, stream>>>(src, dst, binCursor, binned,
                                                  n_edges, nb);
    gather_kernel<<<nb, 256, 0, stream>>>(A, (const uint4*)Bh, binOffG, binCount,
                                          binned, out, n_nodes);
}

// Round 9
// 117.179 us; speedup vs baseline: 1.7119x; 1.0939x over previous
//
#include <hip/hip_runtime.h>
#include <math.h>

#define N_CH 128
#define NB_MAX 1024     // max bucket count (n_nodes <= 16384 -> nb <= 1024)
#define ECHUNK 2048     // edges per hist/bin chunk
#define GCHUNK 2048     // records per gather CSR chunk
#define XPAD 8          // bf16 pad per LDS row (16 B) -> breaks bank conflicts
#define XLD (N_CH + XPAD)

typedef __attribute__((ext_vector_type(8))) short bf16x8;
typedef __attribute__((ext_vector_type(4))) float f32x4;

__device__ __forceinline__ unsigned short f2bf(float f) {
    // bf16 round-to-nearest-even
    unsigned int bits = __float_as_uint(f);
    unsigned int r = (bits + 0x7FFFu + ((bits >> 16) & 1u)) >> 16;
    return (unsigned short)r;
}

// ---------------------------------------------------------------------------
// K0: weight prep -> bf16, k-major per output: Vb[o*128+k]. Zero binCount.
//   V1b[o][k] = bf16(W[o][k] - W[o][128+k]),  V2b[o][k] = bf16(W[o][128+k])
// ---------------------------------------------------------------------------
__global__ __launch_bounds__(256) void prep_kernel(const float* __restrict__ W,
                                                   unsigned short* __restrict__ V1b,
                                                   unsigned short* __restrict__ V2b,
                                                   int* __restrict__ binCount,
                                                   int nb) {
    int i = blockIdx.x * 256 + threadIdx.x;   // i = o*128 + k
    if (i < N_CH * N_CH) {
        int o = i >> 7, k = i & 127;
        float w1 = W[o * 256 + k];
        float w2 = W[o * 256 + 128 + k];
        V1b[i] = f2bf(w1 - w2);
        V2b[i] = f2bf(w2);
    }
    if (i < nb) binCount[i] = 0;
}

// ---------------------------------------------------------------------------
// K1: fused MFMA GEMM (16 nodes/block, 625 blocks) + LDS bucket histogram
// (bucket = dst>>4; blocks 0..312 cover 2048-edge chunks). No fence/ticket.
// GEMM: A = x@V1 + bias (f32 out), Bh = bf16(x@V2), via mfma_f32_16x16x32_bf16.
//   A-frag: lane l -> xs[l&15][kb*32+(l>>4)*8+j]  (LDS bf16, row pad 16 B)
//   B-frag: lane l -> Vb[obase+t*16+(l&15)][kb*32+(l>>4)*8+j] (16 B global)
//   D: row(node) = (l>>4)*4+r, col(out) = l&15   [m89-verified]
// ---------------------------------------------------------------------------
__global__ __launch_bounds__(256) void gemm_kernel(const float* __restrict__ x,
                                                   const unsigned short* __restrict__ V1b,
                                                   const unsigned short* __restrict__ V2b,
                                                   const float* __restrict__ bias,
                                                   const int* __restrict__ dst,
                                                   float* __restrict__ A,
                                                   unsigned short* __restrict__ Bh,
                                                   int* __restrict__ binCount,
                                                   int n_nodes, int n_edges, int nb) {
    __shared__ unsigned short xs[16][XLD];  // 4.25 KB bf16 x-tile
    __shared__ int h[NB_MAX];               // 4 KB
    const int tid = threadIdx.x;
    const int bid = blockIdx.x;

    // --- LDS bucket histogram of this block's 2048-edge chunk ---
    const int ebase = bid * ECHUNK;
    if (ebase < n_edges) {
        const int ecnt = min(ECHUNK, n_edges - ebase);
        for (int i = tid; i < nb; i += 256) h[i] = 0;
        __syncthreads();
        const int j = tid * 8;
        if (j + 8 <= ecnt) {
            int4 d0 = *(const int4*)(dst + ebase + j);
            int4 d1 = *(const int4*)(dst + ebase + j + 4);
            atomicAdd(&h[d0.x >> 4], 1); atomicAdd(&h[d0.y >> 4], 1);
            atomicAdd(&h[d0.z >> 4], 1); atomicAdd(&h[d0.w >> 4], 1);
            atomicAdd(&h[d1.x >> 4], 1); atomicAdd(&h[d1.y >> 4], 1);
            atomicAdd(&h[d1.z >> 4], 1); atomicAdd(&h[d1.w >> 4], 1);
        } else {
            for (int q = j; q < min(j + 8, ecnt); ++q)
                atomicAdd(&h[dst[ebase + q] >> 4], 1);
        }
        __syncthreads();
        for (int i = tid; i < nb; i += 256)
            if (h[i]) atomicAdd(&binCount[i], h[i]);   // fire-and-forget
    }

    // --- GEMM: 16 nodes per block ---
    const int n0 = bid * 16;
    if (n0 >= n_nodes) return;

    // stage x tile as bf16 into padded LDS
    if (n0 + 16 <= n_nodes) {
        const float4* xg = (const float4*)(x + (size_t)n0 * N_CH);
        #pragma unroll
        for (int i = 0; i < 2; ++i) {
            int f = tid + i * 256;          // 0..511 float4s
            float4 v = xg[f];
            int row = f >> 5, c4 = (f & 31) * 4;
            unsigned short* p = &xs[row][c4];
            p[0] = f2bf(v.x); p[1] = f2bf(v.y); p[2] = f2bf(v.z); p[3] = f2bf(v.w);
        }
    } else {
        for (int i = tid; i < 16 * N_CH; i += 256) {
            int n = n0 + (i >> 7);
            xs[i >> 7][i & 127] = (n < n_nodes) ? f2bf(x[(size_t)n * N_CH + (i & 127)])
                                                : (unsigned short)0;
        }
    }
    __syncthreads();

    const int w  = tid >> 6;        // wave 0..3 -> out cols [w*32, w*32+32)
    const int l  = tid & 63;
    const int lc = l & 15;          // A-row / B-col / D-col lane index
    const int lk = (l >> 4) * 8;    // k sub-offset

    // loop-invariant B fragments: 2 mats x 2 tiles x 4 k-blocks
    const int obase = w * 32;
    bf16x8 b1[2][4], b2[2][4];
    #pragma unroll
    for (int t = 0; t < 2; ++t) {
        const int o = obase + t * 16 + lc;
        #pragma unroll
        for (int kb = 0; kb < 4; ++kb) {
            b1[t][kb] = *(const bf16x8*)(V1b + o * 128 + kb * 32 + lk);
            b2[t][kb] = *(const bf16x8*)(V2b + o * 128 + kb * 32 + lk);
        }
    }

    f32x4 c1[2] = {{0.f,0.f,0.f,0.f},{0.f,0.f,0.f,0.f}};
    f32x4 c2[2] = {{0.f,0.f,0.f,0.f},{0.f,0.f,0.f,0.f}};
    #pragma unroll
    for (int kb = 0; kb < 4; ++kb) {
        bf16x8 a = *(const bf16x8*)(&xs[lc][kb * 32 + lk]);
        #pragma unroll
        for (int t = 0; t < 2; ++t) {
            c1[t] = __builtin_amdgcn_mfma_f32_16x16x32_bf16(a, b1[t][kb], c1[t], 0, 0, 0);
            c2[t] = __builtin_amdgcn_mfma_f32_16x16x32_bf16(a, b2[t][kb], c2[t], 0, 0, 0);
        }
    }

    // epilogue: D row(node) = (l>>4)*4 + r, col(out) = lc
    const int nrow0 = (l >> 4) * 4;
    #pragma unroll
    for (int t = 0; t < 2; ++t) {
        const int o = obase + t * 16 + lc;
        const float bo = bias[o];
        #pragma unroll
        for (int r = 0; r < 4; ++r) {
            const int n = n0 + nrow0 + r;
            if (n < n_nodes) {
                A[(size_t)n * N_CH + o] = c1[t][r] + bo;
                Bh[(size_t)n * N_CH + o] = f2bf(c2[t][r]);
            }
        }
    }
}

// ---------------------------------------------------------------------------
// K2: exclusive scan of bucket counts -> binOffG, binCursor. One block, 1024
// threads, plain coalesced loads (kernel boundary coherence). Regions padded
// to 4 records (16 B alignment).
// ---------------------------------------------------------------------------
__global__ __launch_bounds__(1024) void scan_kernel(const int* __restrict__ binCount,
                                                    int* __restrict__ binOffG,
                                                    int* __restrict__ binCursor,
                                                    int nb) {
    __shared__ int sc[1024];
    const int tid = threadIdx.x;
    int c = (tid < nb) ? binCount[tid] : 0;
    int p = (c + 3) & ~3;
    sc[tid] = p;
    __syncthreads();
    #pragma unroll
    for (int off = 1; off < 1024; off <<= 1) {
        int u = (tid >= off) ? sc[tid - off] : 0;
        __syncthreads();
        sc[tid] += u;
        __syncthreads();
    }
    if (tid < nb) {
        int excl = sc[tid] - p;
        binOffG[tid] = excl;
        binCursor[tid] = excl;
    }
}

// ---------------------------------------------------------------------------
// K3: slim bin scatter: hist -> rank via LDS atomics -> reserve via
// atomicAdd(binCursor) -> direct packed writes (dst&15)<<14 | src.
// ---------------------------------------------------------------------------
__global__ __launch_bounds__(256) void bin_kernel(const int* __restrict__ src,
                                                  const int* __restrict__ dst,
                                                  int* __restrict__ binCursor,
                                                  unsigned int* __restrict__ binned,
                                                  int n_edges, int nb) {
    __shared__ int hist[NB_MAX];    // 4 KB
    __shared__ int rbase[NB_MAX];   // 4 KB
    const int tid = threadIdx.x;
    const int base = blockIdx.x * ECHUNK;
    const int cnt = min(ECHUNK, n_edges - base);

    for (int i = tid; i < nb; i += 256) hist[i] = 0;
    __syncthreads();

    const int j = tid * 8;
    const int mc = max(0, min(8, cnt - j));
    unsigned int pk[8]; int bb[8], rr[8];
    if (mc == 8) {
        int4 s0 = *(const int4*)(src + base + j);
        int4 s1 = *(const int4*)(src + base + j + 4);
        int4 d0 = *(const int4*)(dst + base + j);
        int4 d1 = *(const int4*)(dst + base + j + 4);
        int sv[8] = {s0.x, s0.y, s0.z, s0.w, s1.x, s1.y, s1.z, s1.w};
        int dv[8] = {d0.x, d0.y, d0.z, d0.w, d1.x, d1.y, d1.z, d1.w};
        #pragma unroll
        for (int k = 0; k < 8; ++k) {
            int b = dv[k] >> 4;
            pk[k] = ((unsigned int)(dv[k] & 15) << 14) | (unsigned int)sv[k];
            bb[k] = b;
            rr[k] = atomicAdd(&hist[b], 1);
        }
    } else {
        for (int k = 0; k < mc; ++k) {
            int sv = src[base + j + k];
            int dv = dst[base + j + k];
            int b = dv >> 4;
            pk[k] = ((unsigned int)(dv & 15) << 14) | (unsigned int)sv;
            bb[k] = b;
            rr[k] = atomicAdd(&hist[b], 1);
        }
    }
    __syncthreads();

    for (int i = tid; i < nb; i += 256) {
        int c = hist[i];
        if (c) rbase[i] = atomicAdd(&binCursor[i], c);
    }
    __syncthreads();

    for (int k = 0; k < mc; ++k)
        binned[rbase[bb[k]] + rr[k]] = pk[k];
}

// ---------------------------------------------------------------------------
// K4: fused CSR-build + gather-max. One block (256 thr = 4 waves) per 16-node
// bucket; 16 lanes cover one 256 B Bh row (uint4 = 8 channels/lane); 4
// sub-groups -> 4 edges per wave-load; main loop keeps 8 loads in flight.
// ---------------------------------------------------------------------------
#define FOLD4(acc_lo, acc_hi, a, b, c, d)                                        \
    acc_lo = fmaxf(acc_lo, fmaxf(fmaxf(__uint_as_float((a) << 16),               \
                                       __uint_as_float((b) << 16)),              \
                                 fmaxf(__uint_as_float((c) << 16),               \
                                       __uint_as_float((d) << 16))));            \
    acc_hi = fmaxf(acc_hi, fmaxf(fmaxf(__uint_as_float((a) & 0xFFFF0000u),       \
                                       __uint_as_float((b) & 0xFFFF0000u)),      \
                                 fmaxf(__uint_as_float((c) & 0xFFFF0000u),       \
                                       __uint_as_float((d) & 0xFFFF0000u))));

__global__ __launch_bounds__(256) void gather_kernel(
        const float* __restrict__ A,
        const uint4* __restrict__ Bh4,   // n_nodes x 16 uint4 (128 bf16)
        const int* __restrict__ binOffG,
        const int* __restrict__ binCount,
        const unsigned int* __restrict__ binned,
        float* __restrict__ out,
        int n_nodes) {
    __shared__ int lidx[GCHUNK];        // 8 KB
    __shared__ int h16[16], e17[17];
    const int b = blockIdx.x;
    const int tid = threadIdx.x;
    const int wv  = tid >> 6;           // wave 0..3
    const int l   = tid & 63;
    const int sub = l >> 4;             // edge slot within load group
    const int col = l & 15;             // 16 B column within the 256 B row
    const int rbeg = binOffG[b];
    const int cnt  = binCount[b];

    float mlo[4][4], mhi[4][4]; int tcnt[4];
    #pragma unroll
    for (int i = 0; i < 4; ++i) {
        tcnt[i] = 0;
        #pragma unroll
        for (int u = 0; u < 4; ++u) { mlo[i][u] = -INFINITY; mhi[i][u] = -INFINITY; }
    }

    for (int cb = 0; cb < cnt; cb += GCHUNK) {
        const int ccnt = min(GCHUNK, cnt - cb);
        if (tid < 16) h16[tid] = 0;
        __syncthreads();

        // load + rank this chunk's records (8 per thread)
        const int mb = tid * 8;
        const int mc = max(0, min(8, ccnt - mb));
        int myd[8], mys[8], myr[8];
        if (mc == 8) {
            int4 r0 = *(const int4*)((const int*)binned + rbeg + cb + mb);
            int4 r1 = *(const int4*)((const int*)binned + rbeg + cb + mb + 4);
            unsigned int wv8[8] = {(unsigned int)r0.x, (unsigned int)r0.y,
                                   (unsigned int)r0.z, (unsigned int)r0.w,
                                   (unsigned int)r1.x, (unsigned int)r1.y,
                                   (unsigned int)r1.z, (unsigned int)r1.w};
            #pragma unroll
            for (int k = 0; k < 8; ++k) {
                myd[k] = (int)(wv8[k] >> 14);
                mys[k] = (int)(wv8[k] & 16383u);
                myr[k] = atomicAdd(&h16[myd[k]], 1);
            }
        } else {
            for (int k = 0; k < mc; ++k) {
                unsigned int w = binned[rbeg + cb + mb + k];
                myd[k] = (int)(w >> 14);
                mys[k] = (int)(w & 16383u);
                myr[k] = atomicAdd(&h16[myd[k]], 1);
            }
        }
        __syncthreads();
        if (tid == 0) {
            int s = 0;
            #pragma unroll
            for (int k = 0; k < 16; ++k) { e17[k] = s; s += h16[k]; }
            e17[16] = s;
        }
        __syncthreads();
        for (int k = 0; k < mc; ++k)
            lidx[e17[myd[k]] + myr[k]] = mys[k];
        __syncthreads();

        // gather: 4 nodes per wave, 8 row-loads in flight
        #pragma unroll
        for (int i = 0; i < 4; ++i) {
            const int nl = wv * 4 + i;
            const int c  = h16[nl];
            const int bg = e17[nl];
            tcnt[i] += c;
            int q = 0;
            for (; q + 32 <= c; q += 32) {
                int e[8];
                #pragma unroll
                for (int s = 0; s < 8; ++s) e[s] = lidx[bg + q + 4 * s + sub];
                uint4 w[8];
                #pragma unroll
                for (int s = 0; s < 8; ++s) w[s] = Bh4[(size_t)e[s] * 16 + col];
                FOLD4(mlo[i][0], mhi[i][0], w[0].x, w[1].x, w[2].x, w[3].x);
                FOLD4(mlo[i][1], mhi[i][1], w[0].y, w[1].y, w[2].y, w[3].y);
                FOLD4(mlo[i][2], mhi[i][2], w[0].z, w[1].z, w[2].z, w[3].z);
                FOLD4(mlo[i][3], mhi[i][3], w[0].w, w[1].w, w[2].w, w[3].w);
                FOLD4(mlo[i][0], mhi[i][0], w[4].x, w[5].x, w[6].x, w[7].x);
                FOLD4(mlo[i][1], mhi[i][1], w[4].y, w[5].y, w[6].y, w[7].y);
                FOLD4(mlo[i][2], mhi[i][2], w[4].z, w[5].z, w[6].z, w[7].z);
                FOLD4(mlo[i][3], mhi[i][3], w[4].w, w[5].w, w[6].w, w[7].w);
            }
            for (; q + 16 <= c; q += 16) {
                int e0 = lidx[bg + q + sub];
                int e1 = lidx[bg + q + 4 + sub];
                int e2 = lidx[bg + q + 8 + sub];
                int e3 = lidx[bg + q + 12 + sub];
                uint4 w0 = Bh4[(size_t)e0 * 16 + col];
                uint4 w1 = Bh4[(size_t)e1 * 16 + col];
                uint4 w2 = Bh4[(size_t)e2 * 16 + col];
                uint4 w3 = Bh4[(size_t)e3 * 16 + col];
                FOLD4(mlo[i][0], mhi[i][0], w0.x, w1.x, w2.x, w3.x);
                FOLD4(mlo[i][1], mhi[i][1], w0.y, w1.y, w2.y, w3.y);
                FOLD4(mlo[i][2], mhi[i][2], w0.z, w1.z, w2.z, w3.z);
                FOLD4(mlo[i][3], mhi[i][3], w0.w, w1.w, w2.w, w3.w);
            }
            for (; q < c; q += 4) {
                int r = q + sub;
                if (r < c) {
                    uint4 w = Bh4[(size_t)lidx[bg + r] * 16 + col];
                    mlo[i][0] = fmaxf(mlo[i][0], __uint_as_float(w.x << 16));
                    mhi[i][0] = fmaxf(mhi[i][0], __uint_as_float(w.x & 0xFFFF0000u));
                    mlo[i][1] = fmaxf(mlo[i][1], __uint_as_float(w.y << 16));
                    mhi[i][1] = fmaxf(mhi[i][1], __uint_as_float(w.y & 0xFFFF0000u));
                    mlo[i][2] = fmaxf(mlo[i][2], __uint_as_float(w.z << 16));
                    mhi[i][2] = fmaxf(mhi[i][2], __uint_as_float(w.z & 0xFFFF0000u));
                    mlo[i][3] = fmaxf(mlo[i][3], __uint_as_float(w.w << 16));
                    mhi[i][3] = fmaxf(mhi[i][3], __uint_as_float(w.w & 0xFFFF0000u));
                }
            }
        }
        __syncthreads();
    }

    // epilogue: reduce sub-groups, add A, write (isolated nodes -> 0)
    #pragma unroll
    for (int i = 0; i < 4; ++i) {
        const int n = b * 16 + wv * 4 + i;
        if (n >= n_nodes) continue;
        float lo[4], hi[4];
        #pragma unroll
        for (int u = 0; u < 4; ++u) {
            lo[u] = mlo[i][u]; hi[u] = mhi[i][u];
            lo[u] = fmaxf(lo[u], __shfl_xor(lo[u], 16, 64));
            hi[u] = fmaxf(hi[u], __shfl_xor(hi[u], 16, 64));
            lo[u] = fmaxf(lo[u], __shfl_xor(lo[u], 32, 64));
            hi[u] = fmaxf(hi[u], __shfl_xor(hi[u], 32, 64));
        }
        if (sub == 0) {
            float r8[8];
            if (tcnt[i] > 0) {
                const float4* Arow = (const float4*)(A + (size_t)n * N_CH + col * 8);
                float4 a0 = Arow[0], a1 = Arow[1];
                r8[0] = a0.x + lo[0]; r8[1] = a0.y + hi[0];
                r8[2] = a0.z + lo[1]; r8[3] = a0.w + hi[1];
                r8[4] = a1.x + lo[2]; r8[5] = a1.y + hi[2];
                r8[6] = a1.z + lo[3]; r8[7] = a1.w + hi[3];
            } else {
                #pragma unroll
                for (int j2 = 0; j2 < 8; ++j2) r8[j2] = 0.f;
            }
            float4* orow = (float4*)(out + (size_t)n * N_CH + col * 8);
            orow[0] = make_float4(r8[0], r8[1], r8[2], r8[3]);
            orow[1] = make_float4(r8[4], r8[5], r8[6], r8[7]);
        }
    }
}

// ---------------------------------------------------------------------------
extern "C" void kernel_launch(void* const* d_in, const int* in_sizes, int n_in,
                              void* d_out, int out_size, void* d_ws, size_t ws_size,
                              hipStream_t stream) {
    const float* x = (const float*)d_in[0];
    const float* W = (const float*)d_in[1];
    const float* b = (const float*)d_in[2];
    const int*   ei = (const int*)d_in[3];

    const int n_nodes = in_sizes[0] / N_CH;   // 10000
    const int n_edges = in_sizes[3] / 2;      // 640000
    const int nb = (n_nodes + 15) >> 4;       // 625 buckets of 16 nodes
    const int* src = ei;
    const int* dst = ei + n_edges;
    float* out = (float*)d_out;

    char* ws = (char*)d_ws;
    size_t off = 0;
    auto alloc = [&](size_t bytes) -> void* {
        void* p = ws + off;
        off += (bytes + 255) & ~(size_t)255;
        return p;
    };
    unsigned short* V1b = (unsigned short*)alloc((size_t)N_CH * N_CH * 2);
    unsigned short* V2b = (unsigned short*)alloc((size_t)N_CH * N_CH * 2);
    float* A         = (float*)alloc((size_t)n_nodes * N_CH * 4);
    unsigned short* Bh = (unsigned short*)alloc((size_t)n_nodes * N_CH * 2);
    int*   binCount  = (int*)alloc((size_t)nb * 4);
    int*   binCursor = (int*)alloc((size_t)nb * 4);
    int*   binOffG   = (int*)alloc((size_t)nb * 4);
    unsigned int* binned = (unsigned int*)alloc(((size_t)n_edges + 4 * NB_MAX) * 4);
    (void)ws_size; (void)n_in; (void)out_size;

    const int nodeChunks = (n_nodes + 15) >> 4;                // 625
    const int edgeChunks = (n_edges + ECHUNK - 1) / ECHUNK;    // 313
    const int ng = max(nodeChunks, edgeChunks);                // 625

    prep_kernel  <<<64, 256, 0, stream>>>(W, V1b, V2b, binCount, nb);
    gemm_kernel  <<<ng, 256, 0, stream>>>(x, V1b, V2b, b, dst, A, Bh, binCount,
                                          n_nodes, n_edges, nb);
    scan_kernel  <<<1, 1024, 0, stream>>>(binCount, binOffG, binCursor, nb);
    bin_kernel   <<<edgeChunks, 256, 0, stream>>>(src, dst, binCursor, binned,
                                                  n_edges, nb);
    gather_kernel<<<nb, 256, 0, stream>>>(A, (const uint4*)Bh, binOffG, binCount,
                                          binned, out, n_nodes);
}